// Round 1
// baseline (388.844 us; speedup 1.0000x reference)
//
#include <hip/hip_runtime.h>
#include <math.h>

namespace {
constexpr int NB = 512;   // batches
constexpr int NK = 1024;  // tokens per batch
constexpr int NM = 64;    // interests per batch
constexpr int ND = 128;   // feature dim
constexpr float ALPHA_T_TO_I = 0.3f;
}

// One block per batch. 256 threads = 4 waves. Each thread owns one token row
// per iteration (4 iterations cover K=1024). Row-max (token->interest) kept in
// a per-lane register; col-max (interest->token) via per-wave swizzled LDS
// tile reduced wave-synchronously (no barriers needed inside the k-loop).
__global__ __launch_bounds__(256, 2) void chamfer_main(
    const float* __restrict__ tokens,
    const float* __restrict__ interests,
    float* __restrict__ partial)  // partial[b] = sum_m dist ; partial[NB+b] = sum_k dist
{
  const int b    = blockIdx.x;
  const int tid  = threadIdx.x;
  const int lane = tid & 63;
  const int wave = tid >> 6;

  __shared__ float rnI[NM];              // reciprocal norms of interests
  __shared__ float tile[4][64][64];      // per-wave dot tile, swizzled cols (64 KB)
  __shared__ float waveColMax[4][NM];
  __shared__ float rowSumW[4];

  const float* __restrict__ ib = interests + (size_t)b * NM * ND;
  const float* __restrict__ tb = tokens    + (size_t)b * NK * ND;

  // Phase 0: reciprocal norms of the 64 interest rows (threads 0..63).
  if (tid < NM) {
    const float* ip = ib + tid * ND;
    float s = 0.f;
#pragma unroll
    for (int d0 = 0; d0 < ND; d0 += 4) {
      const float4 v = *reinterpret_cast<const float4*>(ip + d0);
      s = fmaf(v.x, v.x, s); s = fmaf(v.y, v.y, s);
      s = fmaf(v.z, v.z, s); s = fmaf(v.w, v.w, s);
    }
    rnI[tid] = 1.0f / fmaxf(sqrtf(s), 1e-12f);  // torch F.normalize semantics
  }
  __syncthreads();

  float colRun     = -2.0f;  // running max-dot for interest m == lane (this wave's tokens)
  float rowDistSum = 0.0f;   // sum over this thread's tokens of min-dist

  for (int it = 0; it < NK / 256; ++it) {
    const int kk = it * 256 + tid;
    const float* tp = tb + (size_t)kk * ND;

    // Token row into registers (32 x float4 = 128 VGPRs), plus its norm.
    float4 t[ND / 4];
    float s = 0.f;
#pragma unroll
    for (int j = 0; j < ND / 4; ++j) {
      t[j] = *reinterpret_cast<const float4*>(tp + j * 4);
      s = fmaf(t[j].x, t[j].x, s); s = fmaf(t[j].y, t[j].y, s);
      s = fmaf(t[j].z, t[j].z, s); s = fmaf(t[j].w, t[j].w, s);
    }
    const float rnT = 1.0f / fmaxf(sqrtf(s), 1e-12f);

    float maxdot = -2.0f;
#pragma unroll 2
    for (int m = 0; m < NM; ++m) {
      const float* ip = ib + m * ND;  // uniform address -> broadcast / scalar load
      float4 acc = make_float4(0.f, 0.f, 0.f, 0.f);
#pragma unroll
      for (int j = 0; j < ND / 4; ++j) {
        const float4 iv = *reinterpret_cast<const float4*>(ip + j * 4);
        acc.x = fmaf(t[j].x, iv.x, acc.x);
        acc.y = fmaf(t[j].y, iv.y, acc.y);
        acc.z = fmaf(t[j].z, iv.z, acc.z);
        acc.w = fmaf(t[j].w, iv.w, acc.w);
      }
      const float dot = ((acc.x + acc.y) + (acc.z + acc.w)) * (rnT * rnI[m]);
      maxdot = fmaxf(maxdot, dot);
      // Swizzled store: row = this lane's k, col = (m+lane)&63. 2 lanes/bank only.
      tile[wave][lane][(m + lane) & 63] = dot;
    }

    // Row (token -> nearest interest): dist from max dot.
    rowDistSum += sqrtf(fmaxf(2.0f - 2.0f * maxdot, 1e-12f));

    // Col (interest m == lane): wave-synchronous reduce of the swizzled tile.
    float cmax = -2.0f;
#pragma unroll
    for (int k2 = 0; k2 < 64; ++k2)
      cmax = fmaxf(cmax, tile[wave][k2][(lane + k2) & 63]);
    colRun = fmaxf(colRun, cmax);
  }

  waveColMax[wave][lane] = colRun;

  // Block-reduce the per-thread token dist sums.
  float rs = rowDistSum;
#pragma unroll
  for (int off = 32; off; off >>= 1) rs += __shfl_xor(rs, off);
  if (lane == 0) rowSumW[wave] = rs;
  __syncthreads();

  if (tid < NM) {
    const float v = fmaxf(fmaxf(waveColMax[0][tid], waveColMax[1][tid]),
                          fmaxf(waveColMax[2][tid], waveColMax[3][tid]));
    float dist = sqrtf(fmaxf(2.0f - 2.0f * v, 1e-12f));
#pragma unroll
    for (int off = 32; off; off >>= 1) dist += __shfl_xor(dist, off);
    if (tid == 0) {
      partial[b]      = dist;  // sum over the 64 interests of their min-dist
      partial[NB + b] = rowSumW[0] + rowSumW[1] + rowSumW[2] + rowSumW[3];
    }
  }
}

// Deterministic final reduction over the 512 per-batch partials.
__global__ __launch_bounds__(256) void chamfer_finalize(
    const float* __restrict__ partial, float* __restrict__ out)
{
  __shared__ float s1s[256];
  __shared__ float s2s[256];
  const int t = threadIdx.x;
  s1s[t] = partial[t] + partial[t + 256];
  s2s[t] = partial[NB + t] + partial[NB + t + 256];
  __syncthreads();
  for (int off = 128; off; off >>= 1) {
    if (t < off) { s1s[t] += s1s[t + off]; s2s[t] += s2s[t + off]; }
    __syncthreads();
  }
  if (t == 0) {
    const float loss_i_to_t = s1s[0] * (1.0f / (float)(NB * NM));
    const float loss_t_to_i = s2s[0] * (1.0f / (float)(NB * NK));
    out[0] = loss_i_to_t + ALPHA_T_TO_I * loss_t_to_i;
  }
}

extern "C" void kernel_launch(void* const* d_in, const int* in_sizes, int n_in,
                              void* d_out, int out_size, void* d_ws, size_t ws_size,
                              hipStream_t stream) {
  const float* tokens    = (const float*)d_in[0];  // (512, 1024, 128) f32
  const float* interests = (const float*)d_in[1];  // (512, 64, 128) f32
  float* partial = (float*)d_ws;                   // 2*NB floats
  float* out     = (float*)d_out;

  chamfer_main<<<dim3(NB), dim3(256), 0, stream>>>(tokens, interests, partial);
  chamfer_finalize<<<dim3(1), dim3(256), 0, stream>>>(partial, out);
}

// Round 2
// 56.502 us; speedup vs baseline: 6.8819x; 6.8819x over previous
//
#include <hip/hip_runtime.h>
#include <math.h>

namespace {
constexpr int NB = 512;   // batches
constexpr int NK = 1024;  // tokens per batch
constexpr int NM = 64;    // interests per batch
constexpr int ND = 128;   // feature dim
constexpr float ALPHA_T_TO_I = 0.3f;
}

typedef __attribute__((ext_vector_type(8))) short short8;   // 8 bf16 (4 VGPRs) — MFMA A/B frag
typedef __attribute__((ext_vector_type(4))) short short4v;  // 8 B LDS store
typedef __attribute__((ext_vector_type(4))) float f32x4;    // MFMA C/D frag

// fp32 -> bf16 round-to-nearest-even (bit math; no header-type dependence)
__device__ __forceinline__ short f2bf(float f) {
  unsigned u = __builtin_bit_cast(unsigned, f);
  unsigned r = u + 0x7FFFu + ((u >> 16) & 1u);
  return (short)(r >> 16);
}

// One block per batch, 4 waves. Wave w owns token rows [w*256, w*256+256).
// Interests: normalized bf16 in LDS once, then 16 B-frags hoisted to VGPRs.
// Tokens: loaded straight from HBM in fragment order (no LDS), normalized
// in-register, 16 MFMAs per 16-token tile. Row/col maxes via C-layout
// (col = lane&15, row = (lane>>4)*4 + i) + shfl reductions.
__global__ __launch_bounds__(256, 2) void chamfer_mfma(
    const float* __restrict__ tokens,
    const float* __restrict__ interests,
    float* __restrict__ partial)  // [b] = sum_m mindist ; [NB+b] = sum_k mindist
{
  const int b    = blockIdx.x;
  const int tid  = threadIdx.x;
  const int lane = tid & 63;
  const int wave = tid >> 6;

  __shared__ __align__(16) short iLds[NM * ND];  // normalized interests, bf16 row-major (16 KB)
  __shared__ float colW[4][4][16];
  __shared__ float rowW[4];

  const float* __restrict__ ib = interests + (size_t)b * NM * ND;
  const float* __restrict__ tb = tokens    + (size_t)b * NK * ND;

  // ---- Phase 0: interests -> row-normalize -> bf16 LDS (coalesced float4) ----
  for (int it = 0; it < (NM * ND / 4) / 256; ++it) {   // 8 iters
    const int idx = it * 256 + tid;                    // float4 index; row = idx/32
    const float4 v = reinterpret_cast<const float4*>(ib)[idx];
    float s = fmaf(v.x, v.x, fmaf(v.y, v.y, fmaf(v.z, v.z, v.w * v.w)));
    // row spans 32 consecutive (32-aligned) lanes
    s += __shfl_xor(s, 1);  s += __shfl_xor(s, 2);  s += __shfl_xor(s, 4);
    s += __shfl_xor(s, 8);  s += __shfl_xor(s, 16);
    const float rn = 1.0f / fmaxf(sqrtf(s), 1e-12f);
    short4v o;
    o.x = f2bf(v.x * rn); o.y = f2bf(v.y * rn);
    o.z = f2bf(v.z * rn); o.w = f2bf(v.w * rn);
    reinterpret_cast<short4v*>(iLds)[idx] = o;
  }
  __syncthreads();

  // ---- Hoist all 16 B-fragments (4 col-tiles x 4 k-chunks) into VGPRs ----
  // Packing: lane holds I_hat[c*16 + (lane&15)][q*32 + (lane>>4)*8 + i].
  short8 bf[4][4];
#pragma unroll
  for (int c = 0; c < 4; ++c)
#pragma unroll
    for (int q = 0; q < 4; ++q) {
      const int off = (c * 16 + (lane & 15)) * ND + q * 32 + ((lane >> 4) * 8);
      bf[c][q] = *reinterpret_cast<const short8*>(&iLds[off]);
    }

  float colMax[4] = {-2.f, -2.f, -2.f, -2.f};
  float rowSum = 0.f;
  const int rowBase0 = wave * (NK / 4);

#pragma unroll 1
  for (int rt = 0; rt < 16; ++rt) {
    const int row = rowBase0 + rt * 16 + (lane & 15);
    const float* tp = tb + (size_t)row * ND + ((lane >> 4) * 8);

    float4 lo[4], hi[4];
#pragma unroll
    for (int q = 0; q < 4; ++q) {
      lo[q] = *reinterpret_cast<const float4*>(tp + q * 32);
      hi[q] = *reinterpret_cast<const float4*>(tp + q * 32 + 4);
    }
    float ssq = 0.f;
#pragma unroll
    for (int q = 0; q < 4; ++q) {
      ssq = fmaf(lo[q].x, lo[q].x, ssq); ssq = fmaf(lo[q].y, lo[q].y, ssq);
      ssq = fmaf(lo[q].z, lo[q].z, ssq); ssq = fmaf(lo[q].w, lo[q].w, ssq);
      ssq = fmaf(hi[q].x, hi[q].x, ssq); ssq = fmaf(hi[q].y, hi[q].y, ssq);
      ssq = fmaf(hi[q].z, hi[q].z, ssq); ssq = fmaf(hi[q].w, hi[q].w, ssq);
    }
    // full row ssq: combine the 4 lane-groups (lane&15 fixed)
    ssq += __shfl_xor(ssq, 16);
    ssq += __shfl_xor(ssq, 32);
    const float rn = 1.0f / fmaxf(sqrtf(ssq), 1e-12f);

    short8 af[4];
#pragma unroll
    for (int q = 0; q < 4; ++q) {
      short8 a;
      a[0] = f2bf(lo[q].x * rn); a[1] = f2bf(lo[q].y * rn);
      a[2] = f2bf(lo[q].z * rn); a[3] = f2bf(lo[q].w * rn);
      a[4] = f2bf(hi[q].x * rn); a[5] = f2bf(hi[q].y * rn);
      a[6] = f2bf(hi[q].z * rn); a[7] = f2bf(hi[q].w * rn);
      af[q] = a;
    }

    f32x4 acc[4];
#pragma unroll
    for (int c = 0; c < 4; ++c) acc[c] = (f32x4){0.f, 0.f, 0.f, 0.f};
#pragma unroll
    for (int c = 0; c < 4; ++c)
#pragma unroll
      for (int q = 0; q < 4; ++q)
        acc[c] = __builtin_amdgcn_mfma_f32_16x16x32_bf16(af[q], bf[c][q], acc[c], 0, 0, 0);

    // Row-max (token -> nearest interest). Lane holds rows (lane>>4)*4+i, col lane&15 (+16c).
#pragma unroll
    for (int i = 0; i < 4; ++i) {
      float rm = fmaxf(fmaxf(acc[0][i], acc[1][i]), fmaxf(acc[2][i], acc[3][i]));
      rm = fmaxf(rm, __shfl_xor(rm, 1));
      rm = fmaxf(rm, __shfl_xor(rm, 2));
      rm = fmaxf(rm, __shfl_xor(rm, 4));
      rm = fmaxf(rm, __shfl_xor(rm, 8));
      if ((lane & 15) == 0)
        rowSum += sqrtf(fmaxf(2.0f - 2.0f * rm, 1e-12f));
    }
    // Col-max (interest -> nearest token): max over this lane's 4 token rows.
#pragma unroll
    for (int c = 0; c < 4; ++c) {
      const float m01 = fmaxf(acc[c][0], acc[c][1]);
      const float m23 = fmaxf(acc[c][2], acc[c][3]);
      colMax[c] = fmaxf(colMax[c], fmaxf(m01, m23));
    }
  }

  // Combine col-max across the 4 row-groups of the wave.
#pragma unroll
  for (int c = 0; c < 4; ++c) {
    colMax[c] = fmaxf(colMax[c], __shfl_xor(colMax[c], 16));
    colMax[c] = fmaxf(colMax[c], __shfl_xor(colMax[c], 32));
  }
  if (lane < 16)
#pragma unroll
    for (int c = 0; c < 4; ++c) colW[wave][c][lane] = colMax[c];

  // Wave-total token dist sum (nonzero only on lanes 0,16,32,48).
  rowSum += __shfl_xor(rowSum, 1);  rowSum += __shfl_xor(rowSum, 2);
  rowSum += __shfl_xor(rowSum, 4);  rowSum += __shfl_xor(rowSum, 8);
  rowSum += __shfl_xor(rowSum, 16); rowSum += __shfl_xor(rowSum, 32);
  if (lane == 0) rowW[wave] = rowSum;
  __syncthreads();

  if (tid < 64) {
    const int c = tid >> 4, j = tid & 15;
    const float v = fmaxf(fmaxf(colW[0][c][j], colW[1][c][j]),
                          fmaxf(colW[2][c][j], colW[3][c][j]));
    float dist = sqrtf(fmaxf(2.0f - 2.0f * v, 1e-12f));
    dist += __shfl_xor(dist, 1);  dist += __shfl_xor(dist, 2);
    dist += __shfl_xor(dist, 4);  dist += __shfl_xor(dist, 8);
    dist += __shfl_xor(dist, 16); dist += __shfl_xor(dist, 32);
    if (tid == 0) {
      partial[b]      = dist;
      partial[NB + b] = rowW[0] + rowW[1] + rowW[2] + rowW[3];
    }
  }
}

// Deterministic final reduction over the 512 per-batch partials.
__global__ __launch_bounds__(256) void chamfer_finalize(
    const float* __restrict__ partial, float* __restrict__ out)
{
  __shared__ float s1s[256];
  __shared__ float s2s[256];
  const int t = threadIdx.x;
  s1s[t] = partial[t] + partial[t + 256];
  s2s[t] = partial[NB + t] + partial[NB + t + 256];
  __syncthreads();
  for (int off = 128; off; off >>= 1) {
    if (t < off) { s1s[t] += s1s[t + off]; s2s[t] += s2s[t + off]; }
    __syncthreads();
  }
  if (t == 0) {
    const float loss_i_to_t = s1s[0] * (1.0f / (float)(NB * NM));
    const float loss_t_to_i = s2s[0] * (1.0f / (float)(NB * NK));
    out[0] = loss_i_to_t + ALPHA_T_TO_I * loss_t_to_i;
  }
}

extern "C" void kernel_launch(void* const* d_in, const int* in_sizes, int n_in,
                              void* d_out, int out_size, void* d_ws, size_t ws_size,
                              hipStream_t stream) {
  const float* tokens    = (const float*)d_in[0];  // (512, 1024, 128) f32
  const float* interests = (const float*)d_in[1];  // (512, 64, 128) f32
  float* partial = (float*)d_ws;                   // 2*NB floats
  float* out     = (float*)d_out;

  chamfer_mfma<<<dim3(NB), dim3(256), 0, stream>>>(tokens, interests, partial);
  chamfer_finalize<<<dim3(1), dim3(256), 0, stream>>>(partial, out);
}